// Round 3
// baseline (1215.389 us; speedup 1.0000x reference)
//
#include <hip/hip_runtime.h>
#include <hip/hip_cooperative_groups.h>
#include <float.h>
#include <math.h>

namespace cg = cooperative_groups;

#define N_PTS  8192
#define NB     256          // cooperative grid blocks
#define NT     256
#define NCH    64           // candidate chunks (fused kernel)
#define CH     128          // candidates per chunk
#define QPT    8            // queries per thread in NN
#define STEPS  11           // STEPLIM + 1
#define TOLV   1e-4

// ---- fused-kernel ws layout (bytes) ----
#define WS_BUF0   0          // float [N*3]      98304
#define WS_BUF1   98304      // float [N*3]   -> 196608
#define WS_PD2    196608     // float [NCH*N] -> 2293760
#define WS_PIDX   2293760    // u16   [NCH*N] -> 3342336
#define WS_BPART  3342336    // double[32*16] -> 3346432

// ---- fallback (r2) ws layout, based at 4 MiB ----
#define FB_BASE   4194304
#define FB_TEMPPC (FB_BASE + 0)
#define FB_P2F    (FB_BASE + 98304)
#define FB_PIDX   (FB_BASE + 229376)
#define FB_BPART  (FB_BASE + 1277952)
#define FB_ERRH   (FB_BASE + 1294336)
#define FB_DONEH  (FB_BASE + 1294464)
#define BPGRID    128

// ===========================================================================
// Shared math: Kabsch via Jacobi eigendecomposition of H^T H (double).
// ===========================================================================
__device__ void kabsch3(const double H[3][3], const double c1[3], const double c2[3],
                        double R[3][3], double t[3]) {
    double A[3][3];
    for (int i = 0; i < 3; ++i)
        for (int j = 0; j < 3; ++j) {
            double sacc = 0.0;
            for (int k = 0; k < 3; ++k) sacc += H[k][i] * H[k][j];
            A[i][j] = sacc;
        }
    double V[3][3] = {{1,0,0},{0,1,0},{0,0,1}};
    for (int sweep = 0; sweep < 8; ++sweep) {
        const int PQ[3][2] = {{0,1},{0,2},{1,2}};
        for (int m = 0; m < 3; ++m) {
            int p = PQ[m][0], q = PQ[m][1];
            double apq = A[p][q];
            if (fabs(apq) < 1e-300) continue;
            double app = A[p][p], aqq = A[q][q];
            double tau = (aqq - app) / (2.0 * apq);
            double tt = (tau >= 0.0) ? 1.0 / (tau + sqrt(1.0 + tau*tau))
                                     : 1.0 / (tau - sqrt(1.0 + tau*tau));
            double c = 1.0 / sqrt(1.0 + tt*tt), s = tt * c;
            A[p][p] = app - tt * apq;
            A[q][q] = aqq + tt * apq;
            A[p][q] = 0.0; A[q][p] = 0.0;
            int k = 3 - p - q;
            double akp = A[k][p], akq = A[k][q];
            A[k][p] = c*akp - s*akq; A[p][k] = A[k][p];
            A[k][q] = s*akp + c*akq; A[q][k] = A[k][q];
            for (int r = 0; r < 3; ++r) {
                double vp = V[r][p], vq = V[r][q];
                V[r][p] = c*vp - s*vq;
                V[r][q] = s*vp + c*vq;
            }
        }
    }
    double lam[3] = {A[0][0], A[1][1], A[2][2]};
    int ord[3] = {0,1,2};
    for (int i = 0; i < 2; ++i)
        for (int j = i+1; j < 3; ++j)
            if (lam[ord[j]] > lam[ord[i]]) { int tmp = ord[i]; ord[i] = ord[j]; ord[j] = tmp; }
    double v0[3] = {V[0][ord[0]], V[1][ord[0]], V[2][ord[0]]};
    double v1[3] = {V[0][ord[1]], V[1][ord[1]], V[2][ord[1]]};
    double v2[3] = {V[0][ord[2]], V[1][ord[2]], V[2][ord[2]]};

    double u0[3], u1[3], hv2[3];
    for (int i = 0; i < 3; ++i) u0[i] = H[i][0]*v0[0] + H[i][1]*v0[1] + H[i][2]*v0[2];
    double n0 = sqrt(u0[0]*u0[0] + u0[1]*u0[1] + u0[2]*u0[2]);
    n0 = fmax(n0, 1e-300);
    for (int i = 0; i < 3; ++i) u0[i] /= n0;

    for (int i = 0; i < 3; ++i) u1[i] = H[i][0]*v1[0] + H[i][1]*v1[1] + H[i][2]*v1[2];
    double d01 = u1[0]*u0[0] + u1[1]*u0[1] + u1[2]*u0[2];
    for (int i = 0; i < 3; ++i) u1[i] -= d01 * u0[i];
    double n1 = sqrt(u1[0]*u1[0] + u1[1]*u1[1] + u1[2]*u1[2]);
    n1 = fmax(n1, 1e-300);
    for (int i = 0; i < 3; ++i) u1[i] /= n1;

    double u2[3] = {u0[1]*u1[2] - u0[2]*u1[1],
                    u0[2]*u1[0] - u0[0]*u1[2],
                    u0[0]*u1[1] - u0[1]*u1[0]};
    for (int i = 0; i < 3; ++i) hv2[i] = H[i][0]*v2[0] + H[i][1]*v2[1] + H[i][2]*v2[2];
    if (hv2[0]*u2[0] + hv2[1]*u2[1] + hv2[2]*u2[2] < 0.0) {
        v2[0] = -v2[0]; v2[1] = -v2[1]; v2[2] = -v2[2];
    }
    double cx = v1[1]*v2[2] - v1[2]*v2[1];
    double cy = v1[2]*v2[0] - v1[0]*v2[2];
    double cz = v1[0]*v2[1] - v1[1]*v2[0];
    double detV = v0[0]*cx + v0[1]*cy + v0[2]*cz;
    double dsg = (detV < 0.0) ? -1.0 : 1.0;

    for (int i = 0; i < 3; ++i)
        for (int j = 0; j < 3; ++j)
            R[i][j] = v0[i]*u0[j] + v1[i]*u1[j] + dsg * v2[i]*u2[j];
    for (int i = 0; i < 3; ++i)
        t[i] = c2[i] - (R[i][0]*c1[0] + R[i][1]*c1[1] + R[i][2]*c1[2]);
}

__device__ __forceinline__ void build_H(const double s[16], double c1[3], double c2[3],
                                        double H[3][3]) {
    const double Nn = (double)N_PTS;
    c1[0] = s[1]/Nn; c1[1] = s[2]/Nn; c1[2] = s[3]/Nn;
    c2[0] = s[4]/Nn; c2[1] = s[5]/Nn; c2[2] = s[6]/Nn;
    for (int i = 0; i < 3; ++i)
        for (int j = 0; j < 3; ++j)
            H[i][j] = s[7 + 3*i + j] - Nn * c1[i] * c2[j];
}

// 256-thread deterministic block reduce of 16 doubles -> dst[16] (thread 0).
__device__ __forceinline__ void block_reduce16_store(double vals[16], double* dst) {
    #pragma unroll
    for (int k = 0; k < 16; ++k) {
        double v = vals[k];
        #pragma unroll
        for (int off = 32; off > 0; off >>= 1) v += __shfl_down(v, off, 64);
        vals[k] = v;
    }
    __shared__ double sred[4][16];
    int wave = threadIdx.x >> 6;
    int lane = threadIdx.x & 63;
    if (lane == 0) {
        #pragma unroll
        for (int k = 0; k < 16; ++k) sred[wave][k] = vals[k];
    }
    __syncthreads();
    if (threadIdx.x == 0) {
        #pragma unroll
        for (int k = 0; k < 16; ++k)
            dst[k] = sred[0][k] + sred[1][k] + sred[2][k] + sred[3][k];
    }
}

// ===========================================================================
// FUSED cooperative kernel: whole ICP in one dispatch.
// Block mapping: qb = bid & 3 (2048 queries each), cc = bid >> 2 (128 cands).
// ===========================================================================
__global__ void icp_fused(const float* __restrict__ p1, const float* __restrict__ p2,
                          float* __restrict__ buf0, float* __restrict__ buf1,
                          float* __restrict__ pd2, unsigned short* __restrict__ pidx,
                          double* __restrict__ bpart, float* __restrict__ out) {
    cg::grid_group grid = cg::this_grid();
    const int bid = blockIdx.x, tid = threadIdx.x;
    const int qb = bid & 3, cc = bid >> 2;
    const int cbase = cc * CH;

    __shared__ float4 sCand[CH];   // persistent candidate chunk (2 KB)
    __shared__ float  sRt[12];
    __shared__ int    sDone;

    // one-time candidate staging (|s|^2 packed in w)
    if (tid < CH) {
        int c = cbase + tid;
        float x = p2[3*c], y = p2[3*c+1], z = p2[3*c+2];
        sCand[tid] = make_float4(x, y, z, x*x + y*y + z*z);
    }
    __syncthreads();

    double err = __builtin_inf();   // meaningful on thread 0 only
    int done = 0;                   // block-uniform (broadcast via sDone)

    const float* curbuf = buf0;

    for (int it = 0; it <= STEPS; ++it) {
        // ---- gate (ref step 2) + Kabsch (step 3) of iteration it-1 ----
        if (it > 0) {
            if (!done && tid < 64) {
                double sv[16];
                #pragma unroll
                for (int k = 0; k < 16; ++k)
                    sv[k] = (tid < 32) ? bpart[tid*16 + k] : 0.0;
                #pragma unroll
                for (int off = 32; off > 0; off >>= 1) {
                    #pragma unroll
                    for (int k = 0; k < 16; ++k) sv[k] += __shfl_xor(sv[k], off, 64);
                }
                if (tid == 0) {
                    double errnew = sv[0] / (double)N_PTS;
                    double rel = fabs((errnew - err) / err);  // nan on first -> false
                    int nd = (rel < TOLV) ? 1 : 0;
                    if (!nd) {
                        err = errnew;
                        double c1[3], c2[3], H[3][3], Rm[3][3], tv[3];
                        build_H(sv, c1, c2, H);
                        kabsch3(H, c1, c2, Rm, tv);
                        for (int i = 0; i < 3; ++i) {
                            sRt[3*i]   = (float)Rm[i][0];
                            sRt[3*i+1] = (float)Rm[i][1];
                            sRt[3*i+2] = (float)Rm[i][2];
                            sRt[9+i]   = (float)tv[i];
                        }
                    }
                    done = nd;
                }
            }
            if (tid == 0) sDone = done;
            __syncthreads();
            done = sDone;
        }

        // ---- transform (step 4 of it-1) + buffer write + NN (step 1 of it) ----
        const float* src = (it == 0) ? p1 : (((it & 1) == 1) ? buf0 : buf1);
        float* dst = ((it & 1) == 1) ? buf1 : buf0;
        curbuf = dst;
        const int apply = (it > 0) && !done;

        float m2x[QPT], m2y[QPT], m2z[QPT];
        #pragma unroll
        for (int k = 0; k < QPT; ++k) {
            int q = qb*2048 + 256*k + tid;
            float x = src[3*q], y = src[3*q+1], z = src[3*q+2];
            if (apply) {
                float nx = fmaf(sRt[0], x, fmaf(sRt[1], y, fmaf(sRt[2], z, sRt[9])));
                float ny = fmaf(sRt[3], x, fmaf(sRt[4], y, fmaf(sRt[5], z, sRt[10])));
                float nz = fmaf(sRt[6], x, fmaf(sRt[7], y, fmaf(sRt[8], z, sRt[11])));
                x = nx; y = ny; z = nz;
            }
            if (bid < 4) { dst[3*q] = x; dst[3*q+1] = y; dst[3*q+2] = z; }
            m2x[k] = -2.0f*x; m2y[k] = -2.0f*y; m2z[k] = -2.0f*z;
        }

        if (it < STEPS && !done) {
            float best[QPT]; int bj[QPT];
            #pragma unroll
            for (int k = 0; k < QPT; ++k) { best[k] = FLT_MAX; bj[k] = 0; }

#define PROC(SJ, JJ)                                                \
            {                                                       \
                _Pragma("unroll")                                   \
                for (int k = 0; k < QPT; ++k) {                     \
                    float val = fmaf(m2x[k], (SJ).x, (SJ).w);       \
                    val = fmaf(m2y[k], (SJ).y, val);                \
                    val = fmaf(m2z[k], (SJ).z, val);                \
                    if (val < best[k]) { best[k] = val; bj[k] = (JJ); } \
                }                                                   \
            }
            float4 c0 = sCand[0], c1 = sCand[1], c2 = sCand[2], c3 = sCand[3];
            int j = 0;
            #pragma unroll 4
            for (; j < CH - 4; j += 4) {
                float4 n0 = sCand[j+4], n1 = sCand[j+5], n2 = sCand[j+6], n3 = sCand[j+7];
                PROC(c0, j); PROC(c1, j+1); PROC(c2, j+2); PROC(c3, j+3);
                c0 = n0; c1 = n1; c2 = n2; c3 = n3;
            }
            PROC(c0, j); PROC(c1, j+1); PROC(c2, j+2); PROC(c3, j+3);
#undef PROC
            #pragma unroll
            for (int k = 0; k < QPT; ++k) {
                int q = qb*2048 + 256*k + tid;
                pd2 [cc * N_PTS + q] = best[k];
                pidx[cc * N_PTS + q] = (unsigned short)(cbase + bj[k]);
            }
        }
        grid.sync();

        // ---- combine + covariance partial sums (blocks 0..31) ----
        if (it < STEPS) {
            if (!done && bid < 32) {
                int q = bid*256 + tid;
                float best = pd2[q];
                int bi = pidx[q];
                #pragma unroll 8
                for (int c = 1; c < NCH; ++c) {
                    float v  = pd2 [c * N_PTS + q];
                    int   id = pidx[c * N_PTS + q];
                    if (v < best) { best = v; bi = id; }
                }
                float ax = curbuf[3*q], ay = curbuf[3*q+1], az = curbuf[3*q+2];
                float q2 = ax*ax + ay*ay + az*az;
                float d2 = fmaxf(best + q2, 0.0f);
                float dmin = sqrtf(d2);
                float bx = p2[3*bi], by = p2[3*bi+1], bz = p2[3*bi+2];

                double vals[16];
                vals[0] = (double)dmin;
                vals[1] = (double)ax;  vals[2] = (double)ay;  vals[3] = (double)az;
                vals[4] = (double)bx;  vals[5] = (double)by;  vals[6] = (double)bz;
                vals[7]  = (double)ax * bx; vals[8]  = (double)ax * by; vals[9]  = (double)ax * bz;
                vals[10] = (double)ay * bx; vals[11] = (double)ay * by; vals[12] = (double)ay * bz;
                vals[13] = (double)az * bx; vals[14] = (double)az * by; vals[15] = (double)az * bz;
                block_reduce16_store(vals, bpart + bid * 16);
            }
            grid.sync();
        }
    }

    // ---- final fit: a = p1, b = final coords (buf1 since STEPS is odd) ----
    if (bid < 32) {
        int q = bid*256 + tid;
        float ax = p1[3*q], ay = p1[3*q+1], az = p1[3*q+2];
        float bx = buf1[3*q], by = buf1[3*q+1], bz = buf1[3*q+2];
        double vals[16];
        vals[0] = 0.0;
        vals[1] = (double)ax;  vals[2] = (double)ay;  vals[3] = (double)az;
        vals[4] = (double)bx;  vals[5] = (double)by;  vals[6] = (double)bz;
        vals[7]  = (double)ax * bx; vals[8]  = (double)ax * by; vals[9]  = (double)ax * bz;
        vals[10] = (double)ay * bx; vals[11] = (double)ay * by; vals[12] = (double)ay * bz;
        vals[13] = (double)az * bx; vals[14] = (double)az * by; vals[15] = (double)az * bz;
        block_reduce16_store(vals, bpart + bid * 16);
    }
    grid.sync();

    if (bid == 0 && tid < 64) {
        double sv[16];
        #pragma unroll
        for (int k = 0; k < 16; ++k)
            sv[k] = (tid < 32) ? bpart[tid*16 + k] : 0.0;
        #pragma unroll
        for (int off = 32; off > 0; off >>= 1) {
            #pragma unroll
            for (int k = 0; k < 16; ++k) sv[k] += __shfl_xor(sv[k], off, 64);
        }
        if (tid == 0) {
            double c1[3], c2[3], H[3][3], Rm[3][3], tv[3];
            build_H(sv, c1, c2, H);
            kabsch3(H, c1, c2, Rm, tv);
            for (int i = 0; i < 3; ++i) {
                out[4*i + 0] = (float)Rm[i][0];
                out[4*i + 1] = (float)Rm[i][1];
                out[4*i + 2] = (float)Rm[i][2];
                out[4*i + 3] = (float)tv[i];
            }
        }
    }
}

// ===========================================================================
// FALLBACK: proven round-2 multi-kernel path (used only if cooperative launch
// is unavailable / not capturable).
// ===========================================================================
__global__ void fb_init(const float* __restrict__ p1, const float* __restrict__ p2,
                        float* __restrict__ temppc, float4* __restrict__ p2f,
                        double* __restrict__ err_hist, int* __restrict__ done_hist) {
    int i = blockIdx.x * blockDim.x + threadIdx.x;
    if (i < N_PTS) {
        float x = p2[3*i], y = p2[3*i+1], z = p2[3*i+2];
        p2f[i] = make_float4(x, y, z, x*x + y*y + z*z);
        temppc[3*i]   = p1[3*i];
        temppc[3*i+1] = p1[3*i+1];
        temppc[3*i+2] = p1[3*i+2];
    }
    if (i == 0) { err_hist[0] = __builtin_inf(); done_hist[0] = 0; }
}

__global__ void fb_nn_partial(const float* __restrict__ temppc, const float4* __restrict__ p2f,
                              unsigned short* __restrict__ pidx,
                              const int* __restrict__ done_hist, int it) {
    if (done_hist[it]) return;
    __shared__ float4 s[CH];
    int qb = blockIdx.x, cc = blockIdx.y, tid = threadIdx.x;
    int cbase = cc * CH;
    if (tid < CH) s[tid] = p2f[cbase + tid];
    __syncthreads();
    int q0 = qb * 1024 + tid;
    float m2x[4], m2y[4], m2z[4], best[4]; int bj[4];
    #pragma unroll
    for (int k = 0; k < 4; ++k) {
        int q = q0 + 256*k;
        m2x[k] = -2.0f * temppc[3*q];
        m2y[k] = -2.0f * temppc[3*q+1];
        m2z[k] = -2.0f * temppc[3*q+2];
        best[k] = FLT_MAX; bj[k] = 0;
    }
#define FPROC(SJ, JJ)                                            \
    {                                                            \
        _Pragma("unroll")                                        \
        for (int k = 0; k < 4; ++k) {                            \
            float val = fmaf(m2x[k], (SJ).x, (SJ).w);            \
            val = fmaf(m2y[k], (SJ).y, val);                     \
            val = fmaf(m2z[k], (SJ).z, val);                     \
            if (val < best[k]) { best[k] = val; bj[k] = (JJ); }  \
        }                                                        \
    }
    float4 c0 = s[0], c1 = s[1], c2 = s[2], c3 = s[3];
    int j = 0;
    #pragma unroll 4
    for (; j < CH - 4; j += 4) {
        float4 n0 = s[j+4], n1 = s[j+5], n2 = s[j+6], n3 = s[j+7];
        FPROC(c0, j); FPROC(c1, j+1); FPROC(c2, j+2); FPROC(c3, j+3);
        c0 = n0; c1 = n1; c2 = n2; c3 = n3;
    }
    FPROC(c0, j); FPROC(c1, j+1); FPROC(c2, j+2); FPROC(c3, j+3);
#undef FPROC
    #pragma unroll
    for (int k = 0; k < 4; ++k)
        pidx[cc * N_PTS + q0 + 256*k] = (unsigned short)(cbase + bj[k]);
}

__device__ __forceinline__ void fb_wave_reduce16_store(double vals[16], double* dst) {
    int lane = threadIdx.x & 63;
    #pragma unroll
    for (int k = 0; k < 16; ++k) {
        double v = vals[k];
        #pragma unroll
        for (int off = 32; off > 0; off >>= 1) v += __shfl_down(v, off, 64);
        if (lane == 0) dst[k] = v;
    }
}

__global__ void fb_nn_combine(const float* __restrict__ temppc, const float4* __restrict__ p2f,
                              const unsigned short* __restrict__ pidx,
                              double* __restrict__ bpart,
                              const int* __restrict__ done_hist, int it) {
    if (done_hist[it]) return;
    int q = blockIdx.x * 64 + threadIdx.x;
    float ax = temppc[3*q], ay = temppc[3*q+1], az = temppc[3*q+2];
    float m2x = -2.0f*ax, m2y = -2.0f*ay, m2z = -2.0f*az;
    float best = FLT_MAX; int bi = 0;
    #pragma unroll 8
    for (int c = 0; c < NCH; ++c) {
        int idx = pidx[c * N_PTS + q];
        float4 sj = p2f[idx];
        float val = fmaf(m2x, sj.x, sj.w);
        val = fmaf(m2y, sj.y, val);
        val = fmaf(m2z, sj.z, val);
        if (val < best) { best = val; bi = idx; }
    }
    float q2 = ax*ax + ay*ay + az*az;
    float d2 = fmaxf(best + q2, 0.0f);
    float dmin = sqrtf(d2);
    float4 b = p2f[bi];
    double vals[16];
    vals[0] = (double)dmin;
    vals[1] = (double)ax;  vals[2] = (double)ay;  vals[3] = (double)az;
    vals[4] = (double)b.x; vals[5] = (double)b.y; vals[6] = (double)b.z;
    vals[7]  = (double)ax * b.x; vals[8]  = (double)ax * b.y; vals[9]  = (double)ax * b.z;
    vals[10] = (double)ay * b.x; vals[11] = (double)ay * b.y; vals[12] = (double)ay * b.z;
    vals[13] = (double)az * b.x; vals[14] = (double)az * b.y; vals[15] = (double)az * b.z;
    fb_wave_reduce16_store(vals, bpart + blockIdx.x * 16);
}

__global__ void fb_fit_partial(const float* __restrict__ a, const float* __restrict__ b,
                               double* __restrict__ bpart) {
    int q = blockIdx.x * 64 + threadIdx.x;
    float ax = a[3*q], ay = a[3*q+1], az = a[3*q+2];
    float bx = b[3*q], by = b[3*q+1], bz = b[3*q+2];
    double vals[16];
    vals[0] = 0.0;
    vals[1] = (double)ax;  vals[2] = (double)ay;  vals[3] = (double)az;
    vals[4] = (double)bx;  vals[5] = (double)by;  vals[6] = (double)bz;
    vals[7]  = (double)ax * bx; vals[8]  = (double)ax * by; vals[9]  = (double)ax * bz;
    vals[10] = (double)ay * bx; vals[11] = (double)ay * by; vals[12] = (double)ay * bz;
    vals[13] = (double)az * bx; vals[14] = (double)az * by; vals[15] = (double)az * bz;
    fb_wave_reduce16_store(vals, bpart + blockIdx.x * 16);
}

__device__ __forceinline__ void fb_sum_bpart(const double* __restrict__ bpart, double s[16]) {
    for (int k = 0; k < 16; ++k) s[k] = 0.0;
    for (int b = 0; b < BPGRID; ++b)
        for (int k = 0; k < 16; ++k) s[k] += bpart[b*16 + k];
}

__global__ void fb_update_transform(const double* __restrict__ bpart,
                                    float* __restrict__ temppc,
                                    double* __restrict__ err_hist,
                                    int* __restrict__ done_hist, int it) {
    __shared__ float sRt[12];
    __shared__ int   snd;
    if (done_hist[it]) {
        if (blockIdx.x == 0 && threadIdx.x == 0) {
            err_hist[it+1]  = err_hist[it];
            done_hist[it+1] = 1;
        }
        return;
    }
    if (threadIdx.x == 0) {
        double s[16];
        fb_sum_bpart(bpart, s);
        double errnew = s[0] / (double)N_PTS;
        double err = err_hist[it];
        double rel = fabs((errnew - err) / err);
        int nd = (rel < TOLV) ? 1 : 0;
        if (blockIdx.x == 0) {
            err_hist[it+1]  = nd ? err : errnew;
            done_hist[it+1] = nd;
        }
        snd = nd;
        if (!nd) {
            double c1[3], c2[3], H[3][3], R[3][3], t[3];
            build_H(s, c1, c2, H);
            kabsch3(H, c1, c2, R, t);
            for (int i = 0; i < 3; ++i) {
                sRt[3*i]   = (float)R[i][0];
                sRt[3*i+1] = (float)R[i][1];
                sRt[3*i+2] = (float)R[i][2];
                sRt[9+i]   = (float)t[i];
            }
        }
    }
    __syncthreads();
    if (snd) return;
    int i = blockIdx.x * 256 + threadIdx.x;
    float x = temppc[3*i], y = temppc[3*i+1], z = temppc[3*i+2];
    float nx = fmaf(sRt[0], x, fmaf(sRt[1], y, fmaf(sRt[2], z, sRt[9])));
    float ny = fmaf(sRt[3], x, fmaf(sRt[4], y, fmaf(sRt[5], z, sRt[10])));
    float nz = fmaf(sRt[6], x, fmaf(sRt[7], y, fmaf(sRt[8], z, sRt[11])));
    temppc[3*i]   = nx;
    temppc[3*i+1] = ny;
    temppc[3*i+2] = nz;
}

__global__ void fb_final_svd(const double* __restrict__ bpart, float* __restrict__ out) {
    if (threadIdx.x != 0 || blockIdx.x != 0) return;
    double s[16];
    fb_sum_bpart(bpart, s);
    double c1[3], c2[3], H[3][3], R[3][3], t[3];
    build_H(s, c1, c2, H);
    kabsch3(H, c1, c2, R, t);
    for (int i = 0; i < 3; ++i) {
        out[4*i + 0] = (float)R[i][0];
        out[4*i + 1] = (float)R[i][1];
        out[4*i + 2] = (float)R[i][2];
        out[4*i + 3] = (float)t[i];
    }
}

// ===========================================================================
extern "C" void kernel_launch(void* const* d_in, const int* in_sizes, int n_in,
                              void* d_out, int out_size, void* d_ws, size_t ws_size,
                              hipStream_t stream) {
    const float* p1 = (const float*)d_in[0];
    const float* p2 = (const float*)d_in[1];
    float* out = (float*)d_out;
    char* ws = (char*)d_ws;

    float*          buf0  = (float*)         (ws + WS_BUF0);
    float*          buf1  = (float*)         (ws + WS_BUF1);
    float*          pd2   = (float*)         (ws + WS_PD2);
    unsigned short* pidx  = (unsigned short*)(ws + WS_PIDX);
    double*         bpart = (double*)        (ws + WS_BPART);

    void* args[] = { (void*)&p1, (void*)&p2, (void*)&buf0, (void*)&buf1,
                     (void*)&pd2, (void*)&pidx, (void*)&bpart, (void*)&out };
    hipError_t e = hipLaunchCooperativeKernel((const void*)icp_fused,
                                              dim3(NB), dim3(NT), args, 0, stream);
    if (e != hipSuccess) {
        (void)hipGetLastError();  // clear error, take fallback path
        float*          temppc    = (float*)         (ws + FB_TEMPPC);
        float4*         p2f       = (float4*)        (ws + FB_P2F);
        unsigned short* fpidx     = (unsigned short*)(ws + FB_PIDX);
        double*         fbpart    = (double*)        (ws + FB_BPART);
        double*         err_hist  = (double*)        (ws + FB_ERRH);
        int*            done_hist = (int*)           (ws + FB_DONEH);

        fb_init<<<32, 256, 0, stream>>>(p1, p2, temppc, p2f, err_hist, done_hist);
        for (int it = 0; it < STEPS; ++it) {
            fb_nn_partial<<<dim3(8, NCH), 256, 0, stream>>>(temppc, p2f, fpidx, done_hist, it);
            fb_nn_combine<<<BPGRID, 64, 0, stream>>>(temppc, p2f, fpidx, fbpart, done_hist, it);
            fb_update_transform<<<32, 256, 0, stream>>>(fbpart, temppc, err_hist, done_hist, it);
        }
        fb_fit_partial<<<BPGRID, 64, 0, stream>>>(p1, temppc, fbpart);
        fb_final_svd<<<1, 64, 0, stream>>>(fbpart, out);
    }
}

// Round 4
// 406.372 us; speedup vs baseline: 2.9908x; 2.9908x over previous
//
#include <hip/hip_runtime.h>
#include <float.h>
#include <math.h>

#define N_PTS 8192
#define NB    256         // blocks (1 per CU)
#define NT    256         // threads per block
#define QPB   32          // queries per block
#define PHC   4096        // candidates staged per phase
#define NR    16          // candidate ranges (tid>>4)
#define RC    256         // candidates per range per phase
#define STEPS 11          // STEPLIM + 1
#define TOLV  1e-4

#define PADSLOT(i) ((i) + ((i) >> 6))
#define SCAND_SZ (PHC + PHC/64)    // 4160 float4 slots

// ---- ws layout (bytes) ----
#define WS_P2F    0         // float4[8192]     = 131072
#define WS_TEMPPC 131072    // float [24576]    =  98304 -> 229376
#define WS_BPA    229376    // double[256*16]   =  32768 -> 262144
#define WS_BPB    262144    // double[256*16]   =  32768 -> 294912
#define WS_ERRH   294912    // double[16]       ->  295040
#define WS_DONEH  295040    // int[16]

// ===========================================================================
// Kabsch via Jacobi eigendecomposition of H^T H (double, single thread).
// ===========================================================================
__device__ void kabsch3(const double H[3][3], const double c1[3], const double c2[3],
                        double R[3][3], double t[3]) {
    double A[3][3];
    for (int i = 0; i < 3; ++i)
        for (int j = 0; j < 3; ++j) {
            double sacc = 0.0;
            for (int k = 0; k < 3; ++k) sacc += H[k][i] * H[k][j];
            A[i][j] = sacc;
        }
    double V[3][3] = {{1,0,0},{0,1,0},{0,0,1}};
    for (int sweep = 0; sweep < 6; ++sweep) {
        const int PQ[3][2] = {{0,1},{0,2},{1,2}};
        for (int mm = 0; mm < 3; ++mm) {
            int p = PQ[mm][0], q = PQ[mm][1];
            double apq = A[p][q];
            if (fabs(apq) < 1e-300) continue;
            double app = A[p][p], aqq = A[q][q];
            double tau = (aqq - app) / (2.0 * apq);
            double tt = (tau >= 0.0) ? 1.0 / (tau + sqrt(1.0 + tau*tau))
                                     : 1.0 / (tau - sqrt(1.0 + tau*tau));
            double c = 1.0 / sqrt(1.0 + tt*tt), s = tt * c;
            A[p][p] = app - tt * apq;
            A[q][q] = aqq + tt * apq;
            A[p][q] = 0.0; A[q][p] = 0.0;
            int k = 3 - p - q;
            double akp = A[k][p], akq = A[k][q];
            A[k][p] = c*akp - s*akq; A[p][k] = A[k][p];
            A[k][q] = s*akp + c*akq; A[q][k] = A[k][q];
            for (int r = 0; r < 3; ++r) {
                double vp = V[r][p], vq = V[r][q];
                V[r][p] = c*vp - s*vq;
                V[r][q] = s*vp + c*vq;
            }
        }
    }
    double lam[3] = {A[0][0], A[1][1], A[2][2]};
    int ord[3] = {0,1,2};
    for (int i = 0; i < 2; ++i)
        for (int j = i+1; j < 3; ++j)
            if (lam[ord[j]] > lam[ord[i]]) { int tmp = ord[i]; ord[i] = ord[j]; ord[j] = tmp; }
    double v0[3] = {V[0][ord[0]], V[1][ord[0]], V[2][ord[0]]};
    double v1[3] = {V[0][ord[1]], V[1][ord[1]], V[2][ord[1]]};
    double v2[3] = {V[0][ord[2]], V[1][ord[2]], V[2][ord[2]]};

    double u0[3], u1[3], hv2[3];
    for (int i = 0; i < 3; ++i) u0[i] = H[i][0]*v0[0] + H[i][1]*v0[1] + H[i][2]*v0[2];
    double n0 = sqrt(u0[0]*u0[0] + u0[1]*u0[1] + u0[2]*u0[2]);
    n0 = fmax(n0, 1e-300);
    for (int i = 0; i < 3; ++i) u0[i] /= n0;

    for (int i = 0; i < 3; ++i) u1[i] = H[i][0]*v1[0] + H[i][1]*v1[1] + H[i][2]*v1[2];
    double d01 = u1[0]*u0[0] + u1[1]*u0[1] + u1[2]*u0[2];
    for (int i = 0; i < 3; ++i) u1[i] -= d01 * u0[i];
    double n1 = sqrt(u1[0]*u1[0] + u1[1]*u1[1] + u1[2]*u1[2]);
    n1 = fmax(n1, 1e-300);
    for (int i = 0; i < 3; ++i) u1[i] /= n1;

    double u2[3] = {u0[1]*u1[2] - u0[2]*u1[1],
                    u0[2]*u1[0] - u0[0]*u1[2],
                    u0[0]*u1[1] - u0[1]*u1[0]};
    for (int i = 0; i < 3; ++i) hv2[i] = H[i][0]*v2[0] + H[i][1]*v2[1] + H[i][2]*v2[2];
    if (hv2[0]*u2[0] + hv2[1]*u2[1] + hv2[2]*u2[2] < 0.0) {
        v2[0] = -v2[0]; v2[1] = -v2[1]; v2[2] = -v2[2];
    }
    double cx = v1[1]*v2[2] - v1[2]*v2[1];
    double cy = v1[2]*v2[0] - v1[0]*v2[2];
    double cz = v1[0]*v2[1] - v1[1]*v2[0];
    double detV = v0[0]*cx + v0[1]*cy + v0[2]*cz;
    double dsg = (detV < 0.0) ? -1.0 : 1.0;

    for (int i = 0; i < 3; ++i)
        for (int j = 0; j < 3; ++j)
            R[i][j] = v0[i]*u0[j] + v1[i]*u1[j] + dsg * v2[i]*u2[j];
    for (int i = 0; i < 3; ++i)
        t[i] = c2[i] - (R[i][0]*c1[0] + R[i][1]*c1[1] + R[i][2]*c1[2]);
}

__device__ __forceinline__ void build_H(const double s[16], double c1[3], double c2[3],
                                        double H[3][3]) {
    const double Nn = (double)N_PTS;
    c1[0] = s[1]/Nn; c1[1] = s[2]/Nn; c1[2] = s[3]/Nn;
    c2[0] = s[4]/Nn; c2[1] = s[5]/Nn; c2[2] = s[6]/Nn;
    for (int i = 0; i < 3; ++i)
        for (int j = 0; j < 3; ++j)
            H[i][j] = s[7 + 3*i + j] - Nn * c1[i] * c2[j];
}

// ---------------------------------------------------------------------------
__global__ void icp_init(const float* __restrict__ p2, float4* __restrict__ p2f,
                         double* __restrict__ err_hist, int* __restrict__ done_hist) {
    int i = blockIdx.x * blockDim.x + threadIdx.x;
    if (i < N_PTS) {
        float x = p2[3*i], y = p2[3*i+1], z = p2[3*i+2];
        p2f[i] = make_float4(x, y, z, x*x + y*y + z*z);
    }
    if (i == 0) { err_hist[0] = __builtin_inf(); done_hist[0] = 0; }
}

// ===========================================================================
// One ICP iteration per dispatch.
//   it in [1,STEPS]: gate+Kabsch+transform for step it-1 (redundant per block)
//   it in [0,STEPS): NN for step it over all 8192 candidates (2 LDS phases)
//   it == STEPS:      final-fit partial sums (p1 vs final coords) instead of NN
// ===========================================================================
__global__ __launch_bounds__(NT) void icp_step(
    const float* __restrict__ p1, const float4* __restrict__ p2f,
    float* __restrict__ temppc,
    const double* __restrict__ bp_prev, double* __restrict__ bp_cur,
    double* __restrict__ err_hist, int* __restrict__ done_hist, int it)
{
    __shared__ float4 sCand[SCAND_SZ];   // 66560 B, bank-padded
    __shared__ float4 sQ[QPB];
    __shared__ float  sWB[4][NR][2];
    __shared__ int    sWI[4][NR][2];
    __shared__ float  sRt[12];
    __shared__ int    sDone;
    const int tid = threadIdx.x, bid = blockIdx.x;

    // ---- gate + Kabsch of step it-1 (redundant per block) ----
    int done = 0;
    if (it > 0) {
        if (tid < 64) {
            double sv[16];
            #pragma unroll
            for (int k = 0; k < 16; ++k) sv[k] = 0.0;
            #pragma unroll
            for (int j = 0; j < 4; ++j) {
                const double* row = bp_prev + (tid + 64*j)*16;
                #pragma unroll
                for (int k = 0; k < 16; ++k) sv[k] += row[k];
            }
            #pragma unroll
            for (int off = 1; off < 64; off <<= 1) {
                #pragma unroll
                for (int k = 0; k < 16; ++k) sv[k] += __shfl_xor(sv[k], off, 64);
            }
            if (tid == 0) {
                double errnew = sv[0] / (double)N_PTS;
                double err = err_hist[it-1];
                int dprev = done_hist[it-1];
                double rel = fabs((errnew - err) / err);   // nan when err=inf -> false
                int nd = dprev | ((rel < TOLV) ? 1 : 0);
                if (bid == 0) { done_hist[it] = nd; err_hist[it] = nd ? err : errnew; }
                sDone = nd;
                if (!nd) {
                    double c1[3], c2[3], H[3][3], Rm[3][3], tv[3];
                    build_H(sv, c1, c2, H);
                    kabsch3(H, c1, c2, Rm, tv);
                    for (int i = 0; i < 3; ++i) {
                        sRt[3*i]   = (float)Rm[i][0];
                        sRt[3*i+1] = (float)Rm[i][1];
                        sRt[3*i+2] = (float)Rm[i][2];
                        sRt[9+i]   = (float)tv[i];
                    }
                }
            }
        }
        __syncthreads();
        done = sDone;
    }

    // ---- own query coords: load, (transform), store, share ----
    if (tid < QPB) {
        int q = bid*QPB + tid;
        float x, y, z;
        if (it == 0) {
            x = p1[3*q]; y = p1[3*q+1]; z = p1[3*q+2];
            temppc[3*q] = x; temppc[3*q+1] = y; temppc[3*q+2] = z;
        } else {
            x = temppc[3*q]; y = temppc[3*q+1]; z = temppc[3*q+2];
            if (!done) {
                float nx = fmaf(sRt[0], x, fmaf(sRt[1], y, fmaf(sRt[2], z, sRt[9])));
                float ny = fmaf(sRt[3], x, fmaf(sRt[4], y, fmaf(sRt[5], z, sRt[10])));
                float nz = fmaf(sRt[6], x, fmaf(sRt[7], y, fmaf(sRt[8], z, sRt[11])));
                x = nx; y = ny; z = nz;
                temppc[3*q] = x; temppc[3*q+1] = y; temppc[3*q+2] = z;
            }
        }
        sQ[tid] = make_float4(x, y, z, x*x + y*y + z*z);
    }
    __syncthreads();

    // ---- final-fit partials (a = p1, b = final coords) ----
    if (it == STEPS) {
        if (tid < 64) {
            double vals[16];
            if (tid < 32) {
                int q = bid*QPB + tid;
                float ax = p1[3*q], ay = p1[3*q+1], az = p1[3*q+2];
                float4 b4 = sQ[tid];
                vals[0] = 0.0;
                vals[1] = (double)ax;   vals[2] = (double)ay;   vals[3] = (double)az;
                vals[4] = (double)b4.x; vals[5] = (double)b4.y; vals[6] = (double)b4.z;
                vals[7]  = (double)ax*b4.x; vals[8]  = (double)ax*b4.y; vals[9]  = (double)ax*b4.z;
                vals[10] = (double)ay*b4.x; vals[11] = (double)ay*b4.y; vals[12] = (double)ay*b4.z;
                vals[13] = (double)az*b4.x; vals[14] = (double)az*b4.y; vals[15] = (double)az*b4.z;
            } else {
                #pragma unroll
                for (int k = 0; k < 16; ++k) vals[k] = 0.0;
            }
            #pragma unroll
            for (int off = 1; off < 32; off <<= 1) {
                #pragma unroll
                for (int k = 0; k < 16; ++k) vals[k] += __shfl_xor(vals[k], off, 64);
            }
            if (tid == 0) {
                double* d = bp_cur + bid*16;
                #pragma unroll
                for (int k = 0; k < 16; ++k) d[k] = vals[k];
            }
        }
        return;
    }

    if (done) return;   // frozen: skip NN (later gates latch via done_hist)

    // ---- NN: 32 queries vs 8192 candidates, 2 LDS phases of 4096 ----
    const int m = tid & 15;      // query pair
    const int r = tid >> 4;      // candidate range
    float4 qa = sQ[2*m], qb = sQ[2*m+1];
    const float ax0 = -2.f*qa.x, ay0 = -2.f*qa.y, az0 = -2.f*qa.z;
    const float ax1 = -2.f*qb.x, ay1 = -2.f*qb.y, az1 = -2.f*qb.z;
    float best0 = FLT_MAX, best1 = FLT_MAX;
    int   bi0 = 0, bi1 = 0;
    const int cb = PADSLOT(r*RC);

#define PROC(SJ, JJ) { \
        float v0 = fmaf(ax0, (SJ).x, (SJ).w); v0 = fmaf(ay0, (SJ).y, v0); v0 = fmaf(az0, (SJ).z, v0); \
        if (v0 < best0) { best0 = v0; bi0 = (JJ); } \
        float v1 = fmaf(ax1, (SJ).x, (SJ).w); v1 = fmaf(ay1, (SJ).y, v1); v1 = fmaf(az1, (SJ).z, v1); \
        if (v1 < best1) { best1 = v1; bi1 = (JJ); } }

    for (int p = 0; p < 2; ++p) {
        for (int i = tid; i < PHC; i += NT) sCand[PADSLOT(i)] = p2f[p*PHC + i];
        __syncthreads();
        const int gb = p*PHC + r*RC;
        float4 c0 = sCand[cb], c1 = sCand[cb+1], c2 = sCand[cb+2], c3 = sCand[cb+3];
        int j = 0;
        #pragma unroll 4
        for (; j < RC - 4; j += 4) {
            int j4 = j + 4;
            float4 n0 = sCand[cb + j4     + ((j4    ) >> 6)];
            float4 n1 = sCand[cb + j4 + 1 + ((j4 + 1) >> 6)];
            float4 n2 = sCand[cb + j4 + 2 + ((j4 + 2) >> 6)];
            float4 n3 = sCand[cb + j4 + 3 + ((j4 + 3) >> 6)];
            PROC(c0, gb + j); PROC(c1, gb + j + 1); PROC(c2, gb + j + 2); PROC(c3, gb + j + 3);
            c0 = n0; c1 = n1; c2 = n2; c3 = n3;
        }
        PROC(c0, gb + j); PROC(c1, gb + j + 1); PROC(c2, gb + j + 2); PROC(c3, gb + j + 3);
        __syncthreads();
    }
#undef PROC

    // ---- combine ranges: wave xor (16,32), then across 4 waves via LDS ----
    #pragma unroll
    for (int off = 16; off <= 32; off <<= 1) {
        float ov0 = __shfl_xor(best0, off, 64); int oi0 = __shfl_xor(bi0, off, 64);
        if (ov0 < best0 || (ov0 == best0 && oi0 < bi0)) { best0 = ov0; bi0 = oi0; }
        float ov1 = __shfl_xor(best1, off, 64); int oi1 = __shfl_xor(bi1, off, 64);
        if (ov1 < best1 || (ov1 == best1 && oi1 < bi1)) { best1 = ov1; bi1 = oi1; }
    }
    const int w = tid >> 6;
    if ((tid & 63) < 16) {
        sWB[w][m][0] = best0; sWI[w][m][0] = bi0;
        sWB[w][m][1] = best1; sWI[w][m][1] = bi1;
    }
    __syncthreads();

    if (tid < 64) {
        double vals[16];
        if (tid < 32) {
            int mm = tid >> 1, wh = tid & 1;
            float bv = sWB[0][mm][wh]; int bi = sWI[0][mm][wh];
            #pragma unroll
            for (int ww = 1; ww < 4; ++ww) {
                float ov = sWB[ww][mm][wh]; int oi = sWI[ww][mm][wh];
                if (ov < bv || (ov == bv && oi < bi)) { bv = ov; bi = oi; }
            }
            float4 a4 = sQ[tid];
            float d2 = fmaxf(bv + a4.w, 0.0f);
            float dmin = sqrtf(d2);
            float4 b4 = p2f[bi];
            vals[0] = (double)dmin;
            vals[1] = (double)a4.x; vals[2] = (double)a4.y; vals[3] = (double)a4.z;
            vals[4] = (double)b4.x; vals[5] = (double)b4.y; vals[6] = (double)b4.z;
            vals[7]  = (double)a4.x*b4.x; vals[8]  = (double)a4.x*b4.y; vals[9]  = (double)a4.x*b4.z;
            vals[10] = (double)a4.y*b4.x; vals[11] = (double)a4.y*b4.y; vals[12] = (double)a4.y*b4.z;
            vals[13] = (double)a4.z*b4.x; vals[14] = (double)a4.z*b4.y; vals[15] = (double)a4.z*b4.z;
        } else {
            #pragma unroll
            for (int k = 0; k < 16; ++k) vals[k] = 0.0;
        }
        #pragma unroll
        for (int off = 1; off < 32; off <<= 1) {
            #pragma unroll
            for (int k = 0; k < 16; ++k) vals[k] += __shfl_xor(vals[k], off, 64);
        }
        if (tid == 0) {
            double* d = bp_cur + bid*16;
            #pragma unroll
            for (int k = 0; k < 16; ++k) d[k] = vals[k];
        }
    }
}

// ---------------------------------------------------------------------------
__global__ void icp_final(const double* __restrict__ bp, float* __restrict__ out) {
    int tid = threadIdx.x;
    double sv[16];
    #pragma unroll
    for (int k = 0; k < 16; ++k) sv[k] = 0.0;
    #pragma unroll
    for (int j = 0; j < 4; ++j) {
        const double* row = bp + (tid + 64*j)*16;
        #pragma unroll
        for (int k = 0; k < 16; ++k) sv[k] += row[k];
    }
    #pragma unroll
    for (int off = 1; off < 64; off <<= 1) {
        #pragma unroll
        for (int k = 0; k < 16; ++k) sv[k] += __shfl_xor(sv[k], off, 64);
    }
    if (tid == 0) {
        double c1[3], c2[3], H[3][3], Rm[3][3], tv[3];
        build_H(sv, c1, c2, H);
        kabsch3(H, c1, c2, Rm, tv);
        for (int i = 0; i < 3; ++i) {
            out[4*i + 0] = (float)Rm[i][0];
            out[4*i + 1] = (float)Rm[i][1];
            out[4*i + 2] = (float)Rm[i][2];
            out[4*i + 3] = (float)tv[i];
        }
    }
}

// ===========================================================================
extern "C" void kernel_launch(void* const* d_in, const int* in_sizes, int n_in,
                              void* d_out, int out_size, void* d_ws, size_t ws_size,
                              hipStream_t stream) {
    const float* p1 = (const float*)d_in[0];
    const float* p2 = (const float*)d_in[1];
    float* out = (float*)d_out;
    char* ws = (char*)d_ws;

    float4* p2f       = (float4*)(ws + WS_P2F);
    float*  temppc    = (float*) (ws + WS_TEMPPC);
    double* bpA       = (double*)(ws + WS_BPA);
    double* bpB       = (double*)(ws + WS_BPB);
    double* err_hist  = (double*)(ws + WS_ERRH);
    int*    done_hist = (int*)   (ws + WS_DONEH);

    icp_init<<<32, 256, 0, stream>>>(p2, p2f, err_hist, done_hist);
    for (int it = 0; it <= STEPS; ++it) {
        double* cur  = (it & 1) ? bpB : bpA;
        double* prev = (it & 1) ? bpA : bpB;
        icp_step<<<NB, NT, 0, stream>>>(p1, p2f, temppc, prev, cur,
                                        err_hist, done_hist, it);
    }
    // STEPS=11 is odd -> last write went to bpB
    icp_final<<<1, 64, 0, stream>>>(bpB, out);
}

// Round 5
// 293.703 us; speedup vs baseline: 4.1382x; 1.3836x over previous
//
#include <hip/hip_runtime.h>
#include <float.h>
#include <math.h>

#define N_PTS 8192
#define NB    256         // blocks (1 per CU)
#define NT    512         // 8 waves/block -> 2 waves/SIMD
#define QPB   32          // queries per block
#define NRG   32          // candidate ranges
#define RC    256         // candidates per range
#define STEPS 11          // STEPLIM + 1
#define TOLV  1e-4

#define PADSLOT(i) ((i) + ((i) >> 6))
#define SC_SZ (N_PTS + N_PTS/64)   // 8320 float4 slots = 133120 B

// ---- ws layout (bytes) ----
#define WS_P2F    0         // float4[8192]   = 131072
#define WS_TEMPPC 131072    // float [24576]  ->  229376
#define WS_BPA    229376    // double[256*16] ->  262144
#define WS_BPB    262144    // double[256*16] ->  294912
#define WS_ERRH   294912    // double[16]     ->  295040
#define WS_DONEH  295040    // int[16]

// ===========================================================================
// Kabsch via Jacobi eigendecomposition of H^T H (double, single thread).
// ===========================================================================
__device__ void kabsch3(const double H[3][3], const double c1[3], const double c2[3],
                        double R[3][3], double t[3]) {
    double A[3][3];
    for (int i = 0; i < 3; ++i)
        for (int j = 0; j < 3; ++j) {
            double sacc = 0.0;
            for (int k = 0; k < 3; ++k) sacc += H[k][i] * H[k][j];
            A[i][j] = sacc;
        }
    double V[3][3] = {{1,0,0},{0,1,0},{0,0,1}};
    for (int sweep = 0; sweep < 6; ++sweep) {
        const int PQ[3][2] = {{0,1},{0,2},{1,2}};
        for (int mm = 0; mm < 3; ++mm) {
            int p = PQ[mm][0], q = PQ[mm][1];
            double apq = A[p][q];
            if (fabs(apq) < 1e-300) continue;
            double app = A[p][p], aqq = A[q][q];
            double tau = (aqq - app) / (2.0 * apq);
            double tt = (tau >= 0.0) ? 1.0 / (tau + sqrt(1.0 + tau*tau))
                                     : 1.0 / (tau - sqrt(1.0 + tau*tau));
            double c = 1.0 / sqrt(1.0 + tt*tt), s = tt * c;
            A[p][p] = app - tt * apq;
            A[q][q] = aqq + tt * apq;
            A[p][q] = 0.0; A[q][p] = 0.0;
            int k = 3 - p - q;
            double akp = A[k][p], akq = A[k][q];
            A[k][p] = c*akp - s*akq; A[p][k] = A[k][p];
            A[k][q] = s*akp + c*akq; A[q][k] = A[k][q];
            for (int r = 0; r < 3; ++r) {
                double vp = V[r][p], vq = V[r][q];
                V[r][p] = c*vp - s*vq;
                V[r][q] = s*vp + c*vq;
            }
        }
    }
    double lam[3] = {A[0][0], A[1][1], A[2][2]};
    int ord[3] = {0,1,2};
    for (int i = 0; i < 2; ++i)
        for (int j = i+1; j < 3; ++j)
            if (lam[ord[j]] > lam[ord[i]]) { int tmp = ord[i]; ord[i] = ord[j]; ord[j] = tmp; }
    double v0[3] = {V[0][ord[0]], V[1][ord[0]], V[2][ord[0]]};
    double v1[3] = {V[0][ord[1]], V[1][ord[1]], V[2][ord[1]]};
    double v2[3] = {V[0][ord[2]], V[1][ord[2]], V[2][ord[2]]};

    double u0[3], u1[3], hv2[3];
    for (int i = 0; i < 3; ++i) u0[i] = H[i][0]*v0[0] + H[i][1]*v0[1] + H[i][2]*v0[2];
    double n0 = sqrt(u0[0]*u0[0] + u0[1]*u0[1] + u0[2]*u0[2]);
    n0 = fmax(n0, 1e-300);
    for (int i = 0; i < 3; ++i) u0[i] /= n0;

    for (int i = 0; i < 3; ++i) u1[i] = H[i][0]*v1[0] + H[i][1]*v1[1] + H[i][2]*v1[2];
    double d01 = u1[0]*u0[0] + u1[1]*u0[1] + u1[2]*u0[2];
    for (int i = 0; i < 3; ++i) u1[i] -= d01 * u0[i];
    double n1 = sqrt(u1[0]*u1[0] + u1[1]*u1[1] + u1[2]*u1[2]);
    n1 = fmax(n1, 1e-300);
    for (int i = 0; i < 3; ++i) u1[i] /= n1;

    double u2[3] = {u0[1]*u1[2] - u0[2]*u1[1],
                    u0[2]*u1[0] - u0[0]*u1[2],
                    u0[0]*u1[1] - u0[1]*u1[0]};
    for (int i = 0; i < 3; ++i) hv2[i] = H[i][0]*v2[0] + H[i][1]*v2[1] + H[i][2]*v2[2];
    if (hv2[0]*u2[0] + hv2[1]*u2[1] + hv2[2]*u2[2] < 0.0) {
        v2[0] = -v2[0]; v2[1] = -v2[1]; v2[2] = -v2[2];
    }
    double cx = v1[1]*v2[2] - v1[2]*v2[1];
    double cy = v1[2]*v2[0] - v1[0]*v2[2];
    double cz = v1[0]*v2[1] - v1[1]*v2[0];
    double detV = v0[0]*cx + v0[1]*cy + v0[2]*cz;
    double dsg = (detV < 0.0) ? -1.0 : 1.0;

    for (int i = 0; i < 3; ++i)
        for (int j = 0; j < 3; ++j)
            R[i][j] = v0[i]*u0[j] + v1[i]*u1[j] + dsg * v2[i]*u2[j];
    for (int i = 0; i < 3; ++i)
        t[i] = c2[i] - (R[i][0]*c1[0] + R[i][1]*c1[1] + R[i][2]*c1[2]);
}

__device__ __forceinline__ void build_H(const double s[16], double c1[3], double c2[3],
                                        double H[3][3]) {
    const double Nn = (double)N_PTS;
    c1[0] = s[1]/Nn; c1[1] = s[2]/Nn; c1[2] = s[3]/Nn;
    c2[0] = s[4]/Nn; c2[1] = s[5]/Nn; c2[2] = s[6]/Nn;
    for (int i = 0; i < 3; ++i)
        for (int j = 0; j < 3; ++j)
            H[i][j] = s[7 + 3*i + j] - Nn * c1[i] * c2[j];
}

// ===========================================================================
// One ICP iteration per dispatch (it = 0..STEPS).
//   it==0 : stage candidates from raw p2 (also writes p2f slice + hist init)
//   it>0  : gate + Kabsch of step it-1 (redundant per block), transform
//   it<STEPS : NN scan (32 queries x 8192 candidates, all in LDS)
//   it==STEPS: final-fit partial sums instead of NN
// ===========================================================================
__global__ __launch_bounds__(NT, 2) void icp_step(
    const float* __restrict__ p1, const float* __restrict__ p2,
    float4* __restrict__ p2f, float* __restrict__ temppc,
    const double* __restrict__ bp_prev, double* __restrict__ bp_cur,
    double* __restrict__ err_hist, int* __restrict__ done_hist, int it)
{
    __shared__ float4 sCand[SC_SZ];      // 133120 B
    __shared__ float4 sQ[QPB];
    __shared__ float  sWB[8][16][2];
    __shared__ int    sWI[8][16][2];
    __shared__ float  sRt[12];
    __shared__ int    sDone;
    const int tid = threadIdx.x, bid = blockIdx.x;

    const int latched = (it > 0) ? done_hist[it-1] : 0;
    const bool scan_possible = (it < STEPS) && !latched;

    // ---- candidate staging (linear, bank-padded; wave-contiguous writes) ----
    if (scan_possible) {
        if (it == 0) {
            #pragma unroll
            for (int k = 0; k < 16; ++k) {
                int i = tid + NT*k;
                float x = p2[3*i], y = p2[3*i+1], z = p2[3*i+2];
                sCand[PADSLOT(i)] = make_float4(x, y, z, x*x + y*y + z*z);
            }
        } else {
            #pragma unroll
            for (int k = 0; k < 16; ++k) {
                int i = tid + NT*k;
                sCand[PADSLOT(i)] = p2f[i];
            }
        }
    }

    // ---- gate + Kabsch of step it-1 ----
    int done = 0;
    if (it == 0) {
        __syncthreads();   // staging complete before p2f slice write
        if (bid == 0 && tid == 0) { err_hist[0] = __builtin_inf(); done_hist[0] = 0; }
        if (tid < QPB) {
            int i = bid*QPB + tid;
            p2f[i] = sCand[PADSLOT(i)];
        }
    } else if (latched) {
        done = 1;
        if (bid == 0 && tid == 0) { done_hist[it] = 1; err_hist[it] = err_hist[it-1]; }
    } else {
        if (tid < 64) {
            double sv[16];
            #pragma unroll
            for (int k = 0; k < 16; ++k) sv[k] = 0.0;
            #pragma unroll
            for (int jj = 0; jj < 4; ++jj) {
                const double* row = bp_prev + (tid + 64*jj)*16;
                #pragma unroll
                for (int k = 0; k < 16; ++k) sv[k] += row[k];
            }
            #pragma unroll
            for (int off = 1; off < 64; off <<= 1) {
                #pragma unroll
                for (int k = 0; k < 16; ++k) sv[k] += __shfl_xor(sv[k], off, 64);
            }
            if (tid == 0) {
                double errnew = sv[0] / (double)N_PTS;
                double err = err_hist[it-1];
                double rel = fabs((errnew - err) / err);   // nan when err=inf -> false
                int nd = (rel < TOLV) ? 1 : 0;
                if (bid == 0) { done_hist[it] = nd; err_hist[it] = nd ? err : errnew; }
                sDone = nd;
                if (!nd) {
                    double c1[3], c2[3], H[3][3], Rm[3][3], tv[3];
                    build_H(sv, c1, c2, H);
                    kabsch3(H, c1, c2, Rm, tv);
                    for (int i = 0; i < 3; ++i) {
                        sRt[3*i]   = (float)Rm[i][0];
                        sRt[3*i+1] = (float)Rm[i][1];
                        sRt[3*i+2] = (float)Rm[i][2];
                        sRt[9+i]   = (float)tv[i];
                    }
                }
            }
        }
        __syncthreads();   // also covers staging
        done = sDone;
    }

    if (done && it < STEPS) return;   // frozen: later gates latch via done_hist

    // ---- own query coords: load, (transform), store, share ----
    if (tid < QPB) {
        int q = bid*QPB + tid;
        float x, y, z;
        if (it == 0) {
            x = p1[3*q]; y = p1[3*q+1]; z = p1[3*q+2];
            temppc[3*q] = x; temppc[3*q+1] = y; temppc[3*q+2] = z;
        } else {
            x = temppc[3*q]; y = temppc[3*q+1]; z = temppc[3*q+2];
            if (!done) {
                float nx = fmaf(sRt[0], x, fmaf(sRt[1], y, fmaf(sRt[2], z, sRt[9])));
                float ny = fmaf(sRt[3], x, fmaf(sRt[4], y, fmaf(sRt[5], z, sRt[10])));
                float nz = fmaf(sRt[6], x, fmaf(sRt[7], y, fmaf(sRt[8], z, sRt[11])));
                x = nx; y = ny; z = nz;
                temppc[3*q] = x; temppc[3*q+1] = y; temppc[3*q+2] = z;
            }
        }
        sQ[tid] = make_float4(x, y, z, x*x + y*y + z*z);
    }
    __syncthreads();

    // ---- final-fit partials (a = p1, b = final coords) ----
    if (it == STEPS) {
        if (tid < 64) {
            double vals[16];
            if (tid < 32) {
                int q = bid*QPB + tid;
                float ax = p1[3*q], ay = p1[3*q+1], az = p1[3*q+2];
                float4 b4 = sQ[tid];
                vals[0] = 0.0;
                vals[1] = (double)ax;   vals[2] = (double)ay;   vals[3] = (double)az;
                vals[4] = (double)b4.x; vals[5] = (double)b4.y; vals[6] = (double)b4.z;
                vals[7]  = (double)ax*b4.x; vals[8]  = (double)ax*b4.y; vals[9]  = (double)ax*b4.z;
                vals[10] = (double)ay*b4.x; vals[11] = (double)ay*b4.y; vals[12] = (double)ay*b4.z;
                vals[13] = (double)az*b4.x; vals[14] = (double)az*b4.y; vals[15] = (double)az*b4.z;
            } else {
                #pragma unroll
                for (int k = 0; k < 16; ++k) vals[k] = 0.0;
            }
            #pragma unroll
            for (int off = 1; off < 32; off <<= 1) {
                #pragma unroll
                for (int k = 0; k < 16; ++k) vals[k] += __shfl_xor(vals[k], off, 64);
            }
            if (tid == 0) {
                double* d = bp_cur + bid*16;
                #pragma unroll
                for (int k = 0; k < 16; ++k) d[k] = vals[k];
            }
        }
        return;
    }

    // ---- NN scan: 16 query-pairs x 32 ranges, 256 candidates each ----
    const int pr = tid & 15;
    const int r  = tid >> 4;
    const float4 qa = sQ[2*pr], qb = sQ[2*pr+1];
    const float ax0 = -2.f*qa.x, ay0 = -2.f*qa.y, az0 = -2.f*qa.z;
    const float ax1 = -2.f*qb.x, ay1 = -2.f*qb.y, az1 = -2.f*qb.z;
    float best0 = FLT_MAX, best1 = FLT_MAX;
    int   bi0 = 0, bi1 = 0;
    const int sb0 = r * 260;    // padded slot base (r*256 + r*4)
    const int gb0 = r * 256;

    for (int jo = 0; jo < 4; ++jo) {
        const int sb = sb0 + jo*65;
        const int gB = gb0 + jo*64;
        #pragma unroll 8
        for (int j = 0; j < 64; ++j) {
            float4 sj = sCand[sb + j];
            int idx = gB + j;
            float v0 = fmaf(ax0, sj.x, sj.w); v0 = fmaf(ay0, sj.y, v0); v0 = fmaf(az0, sj.z, v0);
            if (v0 < best0) { best0 = v0; bi0 = idx; }
            float v1 = fmaf(ax1, sj.x, sj.w); v1 = fmaf(ay1, sj.y, v1); v1 = fmaf(az1, sj.z, v1);
            if (v1 < best1) { best1 = v1; bi1 = idx; }
        }
    }

    // ---- combine ranges: wave xor (16,32), then across 8 waves via LDS ----
    #pragma unroll
    for (int off = 16; off <= 32; off <<= 1) {
        float ov0 = __shfl_xor(best0, off, 64); int oi0 = __shfl_xor(bi0, off, 64);
        if (ov0 < best0 || (ov0 == best0 && oi0 < bi0)) { best0 = ov0; bi0 = oi0; }
        float ov1 = __shfl_xor(best1, off, 64); int oi1 = __shfl_xor(bi1, off, 64);
        if (ov1 < best1 || (ov1 == best1 && oi1 < bi1)) { best1 = ov1; bi1 = oi1; }
    }
    const int w = tid >> 6;
    if ((tid & 63) < 16) {
        sWB[w][pr][0] = best0; sWI[w][pr][0] = bi0;
        sWB[w][pr][1] = best1; sWI[w][pr][1] = bi1;
    }
    __syncthreads();

    if (tid < 64) {
        double vals[16];
        if (tid < 32) {
            int mm = tid >> 1, wh = tid & 1;
            float bv = sWB[0][mm][wh]; int bi = sWI[0][mm][wh];
            #pragma unroll
            for (int ww = 1; ww < 8; ++ww) {
                float ov = sWB[ww][mm][wh]; int oi = sWI[ww][mm][wh];
                if (ov < bv || (ov == bv && oi < bi)) { bv = ov; bi = oi; }
            }
            float4 a4 = sQ[tid];
            float d2 = fmaxf(bv + a4.w, 0.0f);
            float dmin = sqrtf(d2);
            float4 b4 = p2f[bi];
            vals[0] = (double)dmin;
            vals[1] = (double)a4.x; vals[2] = (double)a4.y; vals[3] = (double)a4.z;
            vals[4] = (double)b4.x; vals[5] = (double)b4.y; vals[6] = (double)b4.z;
            vals[7]  = (double)a4.x*b4.x; vals[8]  = (double)a4.x*b4.y; vals[9]  = (double)a4.x*b4.z;
            vals[10] = (double)a4.y*b4.x; vals[11] = (double)a4.y*b4.y; vals[12] = (double)a4.y*b4.z;
            vals[13] = (double)a4.z*b4.x; vals[14] = (double)a4.z*b4.y; vals[15] = (double)a4.z*b4.z;
        } else {
            #pragma unroll
            for (int k = 0; k < 16; ++k) vals[k] = 0.0;
        }
        #pragma unroll
        for (int off = 1; off < 32; off <<= 1) {
            #pragma unroll
            for (int k = 0; k < 16; ++k) vals[k] += __shfl_xor(vals[k], off, 64);
        }
        if (tid == 0) {
            double* d = bp_cur + bid*16;
            #pragma unroll
            for (int k = 0; k < 16; ++k) d[k] = vals[k];
        }
    }
}

// ---------------------------------------------------------------------------
__global__ void icp_final(const double* __restrict__ bp, float* __restrict__ out) {
    int tid = threadIdx.x;
    double sv[16];
    #pragma unroll
    for (int k = 0; k < 16; ++k) sv[k] = 0.0;
    #pragma unroll
    for (int j = 0; j < 4; ++j) {
        const double* row = bp + (tid + 64*j)*16;
        #pragma unroll
        for (int k = 0; k < 16; ++k) sv[k] += row[k];
    }
    #pragma unroll
    for (int off = 1; off < 64; off <<= 1) {
        #pragma unroll
        for (int k = 0; k < 16; ++k) sv[k] += __shfl_xor(sv[k], off, 64);
    }
    if (tid == 0) {
        double c1[3], c2[3], H[3][3], Rm[3][3], tv[3];
        build_H(sv, c1, c2, H);
        kabsch3(H, c1, c2, Rm, tv);
        for (int i = 0; i < 3; ++i) {
            out[4*i + 0] = (float)Rm[i][0];
            out[4*i + 1] = (float)Rm[i][1];
            out[4*i + 2] = (float)Rm[i][2];
            out[4*i + 3] = (float)tv[i];
        }
    }
}

// ===========================================================================
extern "C" void kernel_launch(void* const* d_in, const int* in_sizes, int n_in,
                              void* d_out, int out_size, void* d_ws, size_t ws_size,
                              hipStream_t stream) {
    const float* p1 = (const float*)d_in[0];
    const float* p2 = (const float*)d_in[1];
    float* out = (float*)d_out;
    char* ws = (char*)d_ws;

    float4* p2f       = (float4*)(ws + WS_P2F);
    float*  temppc    = (float*) (ws + WS_TEMPPC);
    double* bpA       = (double*)(ws + WS_BPA);
    double* bpB       = (double*)(ws + WS_BPB);
    double* err_hist  = (double*)(ws + WS_ERRH);
    int*    done_hist = (int*)   (ws + WS_DONEH);

    for (int it = 0; it <= STEPS; ++it) {
        double* cur  = (it & 1) ? bpB : bpA;
        double* prev = (it & 1) ? bpA : bpB;
        icp_step<<<NB, NT, 0, stream>>>(p1, p2, p2f, temppc, prev, cur,
                                        err_hist, done_hist, it);
    }
    // STEPS=11 is odd -> last write went to bpB
    icp_final<<<1, 64, 0, stream>>>(bpB, out);
}